// Round 5
// baseline (753.531 us; speedup 1.0000x reference)
//
#include <hip/hip_runtime.h>
#include <math.h>

#define NPTS 262144
#define MT 64          // points per block
#define XS 328         // LDS activation row stride (bf16): 320 + 8 pad (656 B, 16B-aligned)
#define NWAVE 8

typedef __attribute__((ext_vector_type(8))) short bf16x8;
typedef __attribute__((ext_vector_type(4))) float f32x4;
typedef __attribute__((ext_vector_type(2))) unsigned int u32x2;

#if defined(__has_builtin)
#if __has_builtin(__builtin_amdgcn_cvt_pk_bf16_f32)
#define HAVE_CVT_PK_BF16 1
#endif
#endif

__device__ __forceinline__ short f2bf(float f) {
    union { float f; unsigned u; } v; v.f = f;
    unsigned r = v.u + 0x7fffu + ((v.u >> 16) & 1u);   // RNE
    return (short)(r >> 16);
}
__device__ __forceinline__ unsigned pk2(float a, float b) {
#ifdef HAVE_CVT_PK_BF16
    auto r = __builtin_amdgcn_cvt_pk_bf16_f32(a, b);   // 1 instr, RNE
    unsigned u; __builtin_memcpy(&u, &r, 4);
    return u;
#else
    return ((unsigned)(unsigned short)f2bf(a)) |
           ((unsigned)(unsigned short)f2bf(b) << 16);
#endif
}

// ---- swizzled-weight workspace layout (offsets in bf16 elements) ----
#define OFF_IN   0
#define SZ_IN    (64*256)
#define OFF_H0   (OFF_IN + SZ_IN)
#define SZ_H     (256*256)
#define OFF_H1   (OFF_H0 + SZ_H)
#define OFF_H2   (OFF_H1 + SZ_H)
#define OFF_H3   (OFF_H2 + SZ_H)
#define OFF_H4   (OFF_H3 + SZ_H)
#define SZ_H4    (320*256)
#define OFF_H5   (OFF_H4 + SZ_H4)
#define OFF_H6   (OFF_H5 + SZ_H)
#define OFF_OUT  (OFF_H6 + SZ_H)
#define SZ_OUT   (256*272)          // N padded to 272 = 17 tiles (density tile = 16)
#define OFF_R1   (OFF_OUT + SZ_OUT)
#define SZ_R1    (288*128)
#define OFF_R2   (OFF_R1 + SZ_R1)
#define SZ_R2    (128*16)
#define WS_TOTAL (OFF_R2 + SZ_R2)

// ---------------- weight prep: f32 -> bf16, 16x16x32 fragment swizzle -------
// frag tile (kt,nt): elem ((kt*nNt + nt)*64 + lane)*8 + j
//   holds W[kt*32 + (lane>>4)*8 + j][nt*16 + (lane&15)]  (0-padded)
// Used as A operand of A=W^T (rows = output feature n): A[m=lane&15][k=quad*8+j].
struct PrepP { const float* W[11]; short* ws; };

__global__ __launch_bounds__(256) void prep_all(PrepP pp) {
    int i = blockIdx.x * 256 + threadIdx.x;
    if (i >= WS_TOTAL) return;
    const int offs[12] = {OFF_IN, OFF_H0, OFF_H1, OFF_H2, OFF_H3, OFF_H4,
                          OFF_H5, OFF_H6, OFF_OUT, OFF_R1, OFF_R2, WS_TOTAL};
    const int Ks[11]  = {63,256,256,256,256,319,256,256,256,283,128};
    const int Ns[11]  = {256,256,256,256,256,256,256,256,257,128,3};
    const int Nps[11] = {256,256,256,256,256,256,256,256,272,128,16};
    int seg = 0;
    while (i >= offs[seg + 1]) seg++;
    int li = i - offs[seg];
    int j = li & 7, L = (li >> 3) & 63, tile = li >> 9;
    int nNt = Nps[seg] >> 4;
    int nt = tile % nNt, kt = tile / nNt;
    int k = kt * 32 + ((L >> 4) << 3) + j;
    int n = nt * 16 + (L & 15);
    float v = (k < Ks[seg] && n < Ns[seg]) ? pp.W[seg][k * Ns[seg] + n] : 0.f;
    pp.ws[i] = f2bf(v);
}

// ---------------- fused MLP ----------------
struct Params {
    const float *pos, *dir;
    const float *b_in, *b_h0, *b_h1, *b_h2, *b_h3, *b_h4, *b_h5, *b_h6;
    const float *b_out, *b_r1, *b_r2;
    const short *w;
    float *out;
};

// Transposed MFMA: A = W^T (rows = feature n), B = X^T (cols = point m).
// C layout: row(quad*4+r) = n-in-tile, col(l15) = m-in-tile -> packed b64 stores.
// Wave covers NS n-tiles (ntB..) x TM m-tiles (mtB..); NS*TM == 8 everywhere
// (32 acc regs, under the (512,6) ~85-reg unified cap -> no spill).
// MODE 0: relu -> X.  MODE 1: out layer: features (no relu) -> X; density row
// (tile NT-1, n==256) via a transient 4-wave f32x4 pre-pass straight to gmem.
template<int NKT, int NT, int NS, int TM, int MODE>
__device__ __forceinline__ void layerT(const short* __restrict__ Wsw,
                                       const float* __restrict__ bias,
                                       short* X, float* dout, int p0,
                                       int ntB, int mtB, int wave, int lane) {
    const int l15 = lane & 15, quad = lane >> 4;
    __syncthreads();                      // X (this layer's input) is ready
    const short* xb = X + l15 * XS + quad * 8;

    if (MODE == 1 && wave < 4) {          // density pre-pass: m-tile = wave
        f32x4 ad = (f32x4){0.f, 0.f, 0.f, 0.f};
        for (int kt = 0; kt < NKT; ++kt) {
            bf16x8 b = *(const bf16x8*)(xb + wave * 16 * XS + kt * 32);
            bf16x8 a = *(const bf16x8*)(Wsw + (size_t)((kt * NT + 16) * 64 + lane) * 8);
            ad = __builtin_amdgcn_mfma_f32_16x16x32_bf16(a, b, ad, 0, 0, 0);
        }
        if (quad == 0)                    // C row 0 = n 256 (density)
            dout[3 * NPTS + p0 + wave * 16 + l15] = fmaxf(ad[0] + bias[256], 0.f);
    }

    f32x4 acc[NS][TM];
#pragma unroll
    for (int s = 0; s < NS; s++)
#pragma unroll
        for (int t = 0; t < TM; t++) acc[s][t] = (f32x4){0.f, 0.f, 0.f, 0.f};

    for (int kt = 0; kt < NKT; ++kt) {
        bf16x8 b[TM];
#pragma unroll
        for (int t = 0; t < TM; t++)
            b[t] = *(const bf16x8*)(xb + (mtB + t) * 16 * XS + kt * 32);
#pragma unroll
        for (int s = 0; s < NS; s++) {
            bf16x8 a = *(const bf16x8*)(Wsw + (size_t)((kt * NT + ntB + s) * 64 + lane) * 8);
#pragma unroll
            for (int t = 0; t < TM; t++)
                acc[s][t] = __builtin_amdgcn_mfma_f32_16x16x32_bf16(a, b[t], acc[s][t], 0, 0, 0);
        }
    }
    __syncthreads();                      // all reads of X done; safe to overwrite
#pragma unroll
    for (int s = 0; s < NS; s++) {
        const int n0 = (ntB + s) * 16 + quad * 4;
        const f32x4 bv = *(const f32x4*)(bias + n0);
#pragma unroll
        for (int t = 0; t < TM; t++) {
            const int m = (mtB + t) * 16 + l15;
            float v0 = acc[s][t][0] + bv[0];
            float v1 = acc[s][t][1] + bv[1];
            float v2 = acc[s][t][2] + bv[2];
            float v3 = acc[s][t][3] + bv[3];
            if (MODE == 0) {
                v0 = fmaxf(v0, 0.f); v1 = fmaxf(v1, 0.f);
                v2 = fmaxf(v2, 0.f); v3 = fmaxf(v3, 0.f);
            }
            u32x2 w; w[0] = pk2(v0, v1); w[1] = pk2(v2, v3);
            *(u32x2*)(X + m * XS + n0) = w;
        }
    }
}

__global__ __launch_bounds__(512, 6) void nerf_fused(Params P) {
    __shared__ __align__(16) short X[MT * XS];
    __shared__ __align__(16) short DE[MT * 32];
    const int tid = threadIdx.x;
    const int wave = tid >> 6, lane = tid & 63;
    const int p0 = blockIdx.x * MT;

    // hidden/out layers: NS=4 n-tiles x TM=2 m-tiles per wave
    const int ntB_h = (wave & 3) * 4;
    const int mtB_h = (wave >> 2) * 2;
    // r1 (8 n-tiles x 4 m-tiles): NS=2 x TM=2
    const int ntB_r = (wave & 3) * 2;
    const int mtB_r = (wave >> 2) * 2;

    // ---- positional encodings ----
    for (int i = tid; i < MT * 64; i += 512) {
        const int pt = i >> 6, d = i & 63;
        float v = 0.f;
        if (d < 3) v = P.pos[(p0 + pt) * 3 + d];
        else if (d < 63) {
            const int e = d - 3, f = e / 6, r = e % 6;
            const float x = P.pos[(p0 + pt) * 3 + (r % 3)];
            const float xf = x * (float)(1 << f);
            v = (r < 3) ? sinf(xf) : cosf(xf);
        }
        const short bv = f2bf(v);
        X[pt * XS + d] = bv;               // input-layer operand
        X[pt * XS + 256 + d] = bv;         // h4 skip copy
    }
    for (int i = tid; i < MT * 32; i += 512) {
        const int pt = i >> 5, d = i & 31;
        float v = 0.f;
        if (d < 3) v = P.dir[(p0 + pt) * 3 + d];
        else if (d < 27) {
            const int e = d - 3, f = e / 6, r = e % 6;
            const float x = P.dir[(p0 + pt) * 3 + (r % 3)];
            const float xf = x * (float)(1 << f);
            v = (r < 3) ? sinf(xf) : cosf(xf);
        }
        DE[i] = f2bf(v);
    }

    layerT<2, 16, 4, 2, 0>(P.w + OFF_IN, P.b_in, X, P.out, p0, ntB_h, mtB_h, wave, lane);
    layerT<8, 16, 4, 2, 0>(P.w + OFF_H0, P.b_h0, X, P.out, p0, ntB_h, mtB_h, wave, lane);
    layerT<8, 16, 4, 2, 0>(P.w + OFF_H1, P.b_h1, X, P.out, p0, ntB_h, mtB_h, wave, lane);
    layerT<8, 16, 4, 2, 0>(P.w + OFF_H2, P.b_h2, X, P.out, p0, ntB_h, mtB_h, wave, lane);
    layerT<8, 16, 4, 2, 0>(P.w + OFF_H3, P.b_h3, X, P.out, p0, ntB_h, mtB_h, wave, lane);
    layerT<10, 16, 4, 2, 0>(P.w + OFF_H4, P.b_h4, X, P.out, p0, ntB_h, mtB_h, wave, lane); // concat
    layerT<8, 16, 4, 2, 0>(P.w + OFF_H5, P.b_h5, X, P.out, p0, ntB_h, mtB_h, wave, lane);
    layerT<8, 16, 4, 2, 0>(P.w + OFF_H6, P.b_h6, X, P.out, p0, ntB_h, mtB_h, wave, lane);
    layerT<8, 17, 4, 2, 1>(P.w + OFF_OUT, P.b_out, X, P.out, p0, ntB_h, mtB_h, wave, lane);

    // splice de into cols 256..287 (disjoint from feature cols 0..255; ordered
    // before r1's K-loop by r1's entry barrier; cols 283..287 are real zeros)
    for (int i = tid; i < MT * 32; i += 512) {
        const int pt = i >> 5, d = i & 31;
        X[pt * XS + 256 + d] = DE[i];
    }

    layerT<9, 8, 2, 2, 0>(P.w + OFF_R1, P.b_r1, X, P.out, p0, ntB_r, mtB_r, wave, lane);

    // ---- r2 (128 -> 3) + sigmoid; waves 0..3 each take one 16-point tile ----
    __syncthreads();
    if (wave < 4) {
        const int l15 = lane & 15, quad = lane >> 4;
        f32x4 acc = (f32x4){0.f, 0.f, 0.f, 0.f};
        const short* xb = X + (wave * 16 + l15) * XS + quad * 8;
#pragma unroll
        for (int kt = 0; kt < 4; ++kt) {
            bf16x8 b = *(const bf16x8*)(xb + kt * 32);
            bf16x8 a = *(const bf16x8*)(P.w + OFF_R2 + (size_t)(kt * 64 + lane) * 8);
            acc = __builtin_amdgcn_mfma_f32_16x16x32_bf16(a, b, acc, 0, 0, 0);
        }
        if (quad == 0) {                   // rows r = rgb channel
#pragma unroll
            for (int r = 0; r < 3; r++) {
                const float v = acc[r] + P.b_r2[r];
                P.out[(size_t)(p0 + wave * 16 + l15) * 3 + r] = 1.f / (1.f + expf(-v));
            }
        }
    }
}

extern "C" void kernel_launch(void* const* d_in, const int* in_sizes, int n_in,
                              void* d_out, int out_size, void* d_ws, size_t ws_size,
                              hipStream_t stream) {
    short* ws = (short*)d_ws;

    PrepP pp;
    pp.W[0]  = (const float*)d_in[2];   // W_in
    pp.W[1]  = (const float*)d_in[4];   // W_h0
    pp.W[2]  = (const float*)d_in[6];   // W_h1
    pp.W[3]  = (const float*)d_in[8];   // W_h2
    pp.W[4]  = (const float*)d_in[10];  // W_h3
    pp.W[5]  = (const float*)d_in[12];  // W_h4
    pp.W[6]  = (const float*)d_in[14];  // W_h5
    pp.W[7]  = (const float*)d_in[16];  // W_h6
    pp.W[8]  = (const float*)d_in[18];  // W_out
    pp.W[9]  = (const float*)d_in[20];  // W_r1
    pp.W[10] = (const float*)d_in[22];  // W_r2
    pp.ws = ws;
    hipLaunchKernelGGL(prep_all, dim3((WS_TOTAL + 255) / 256), dim3(256), 0, stream, pp);

    Params P;
    P.pos  = (const float*)d_in[0];
    P.dir  = (const float*)d_in[1];
    P.b_in = (const float*)d_in[3];
    P.b_h0 = (const float*)d_in[5];
    P.b_h1 = (const float*)d_in[7];
    P.b_h2 = (const float*)d_in[9];
    P.b_h3 = (const float*)d_in[11];
    P.b_h4 = (const float*)d_in[13];
    P.b_h5 = (const float*)d_in[15];
    P.b_h6 = (const float*)d_in[17];
    P.b_out = (const float*)d_in[19];
    P.b_r1 = (const float*)d_in[21];
    P.b_r2 = (const float*)d_in[23];
    P.w = ws;
    P.out = (float*)d_out;
    hipLaunchKernelGGL(nerf_fused, dim3(NPTS / MT), dim3(512), 0, stream, P);
}

// Round 6
// 498.397 us; speedup vs baseline: 1.5119x; 1.5119x over previous
//
#include <hip/hip_runtime.h>
#include <math.h>

#define NPTS 262144
#define MT 64          // points per block
#define XS 328         // LDS activation row stride (bf16): 320 + 8 pad (656 B, 16B-aligned)

typedef __attribute__((ext_vector_type(8))) short bf16x8;
typedef __attribute__((ext_vector_type(4))) float f32x4;
typedef __attribute__((ext_vector_type(2))) unsigned int u32x2;

#if defined(__has_builtin)
#if __has_builtin(__builtin_amdgcn_cvt_pk_bf16_f32)
#define HAVE_CVT_PK_BF16 1
#endif
#endif

__device__ __forceinline__ short f2bf(float f) {
    union { float f; unsigned u; } v; v.f = f;
    unsigned r = v.u + 0x7fffu + ((v.u >> 16) & 1u);   // RNE
    return (short)(r >> 16);
}
__device__ __forceinline__ unsigned pk2(float a, float b) {
#ifdef HAVE_CVT_PK_BF16
    auto r = __builtin_amdgcn_cvt_pk_bf16_f32(a, b);   // 1 instr, RNE
    unsigned u; __builtin_memcpy(&u, &r, 4);
    return u;
#else
    return ((unsigned)(unsigned short)f2bf(a)) |
           ((unsigned)(unsigned short)f2bf(b) << 16);
#endif
}

// ---- swizzled-weight workspace layout (offsets in bf16 elements) ----
#define OFF_IN   0
#define SZ_IN    (64*256)
#define OFF_H0   (OFF_IN + SZ_IN)
#define SZ_H     (256*256)
#define OFF_H1   (OFF_H0 + SZ_H)
#define OFF_H2   (OFF_H1 + SZ_H)
#define OFF_H3   (OFF_H2 + SZ_H)
#define OFF_H4   (OFF_H3 + SZ_H)
#define SZ_H4    (320*256)
#define OFF_H5   (OFF_H4 + SZ_H4)
#define OFF_H6   (OFF_H5 + SZ_H)
#define OFF_OUT  (OFF_H6 + SZ_H)
#define SZ_OUT   (256*272)          // N padded to 272 = 17 tiles (density tile = 16)
#define OFF_R1   (OFF_OUT + SZ_OUT)
#define SZ_R1    (288*128)
#define OFF_R2   (OFF_R1 + SZ_R1)
#define SZ_R2    (128*16)
#define WS_TOTAL (OFF_R2 + SZ_R2)

// ---------------- weight prep: f32 -> bf16, 16x16x32 fragment swizzle -------
// frag tile (kt,nt): elem ((kt*nNt + nt)*64 + lane)*8 + j
//   holds W[kt*32 + (lane>>4)*8 + j][nt*16 + (lane&15)]  (0-padded)
// Used as A operand of A=W^T (rows = output feature n): A[m=lane&15][k=quad*8+j].
struct PrepP { const float* W[11]; short* ws; };

__global__ __launch_bounds__(256) void prep_all(PrepP pp) {
    int i = blockIdx.x * 256 + threadIdx.x;
    if (i >= WS_TOTAL) return;
    const int offs[12] = {OFF_IN, OFF_H0, OFF_H1, OFF_H2, OFF_H3, OFF_H4,
                          OFF_H5, OFF_H6, OFF_OUT, OFF_R1, OFF_R2, WS_TOTAL};
    const int Ks[11]  = {63,256,256,256,256,319,256,256,256,283,128};
    const int Ns[11]  = {256,256,256,256,256,256,256,256,257,128,3};
    const int Nps[11] = {256,256,256,256,256,256,256,256,272,128,16};
    int seg = 0;
    while (i >= offs[seg + 1]) seg++;
    int li = i - offs[seg];
    int j = li & 7, L = (li >> 3) & 63, tile = li >> 9;
    int nNt = Nps[seg] >> 4;
    int nt = tile % nNt, kt = tile / nNt;
    int k = kt * 32 + ((L >> 4) << 3) + j;
    int n = nt * 16 + (L & 15);
    float v = (k < Ks[seg] && n < Ns[seg]) ? pp.W[seg][k * Ns[seg] + n] : 0.f;
    pp.ws[i] = f2bf(v);
}

// ---------------- fused MLP ----------------
struct Params {
    const float *pos, *dir;
    const float *b_in, *b_h0, *b_h1, *b_h2, *b_h3, *b_h4, *b_h5, *b_h6;
    const float *b_out, *b_r1, *b_r2;
    const short *w;
    float *out;
};

// Transposed MFMA: A = W^T (rows = feature n), B = X^T (cols = point m).
// C layout: row(quad*4+r) = n-in-tile, col(l15) = m-in-tile -> packed b64 stores.
// 4 waves/block; wave covers NS n-tiles (ntB..) x TM m-tiles (mtB..).
// acc = NS*TM*4 regs; cap at (256,3) is ~170 -> no spill (VGPR_Count is the check).
// MODE 0: relu -> X.  MODE 1: out layer: features (no relu) -> X; density row
// (tile 16, n==256) via a transient 4-wave f32x4 pre-pass straight to gmem.
template<int NKT, int NT, int NS, int TM, int MODE>
__device__ __forceinline__ void layerT(const short* __restrict__ Wsw,
                                       const float* __restrict__ bias,
                                       short* X, float* dout, int p0,
                                       int ntB, int mtB, int wave, int lane) {
    const int l15 = lane & 15, quad = lane >> 4;
    __syncthreads();                      // X (this layer's input) is ready
    const short* xb = X + l15 * XS + quad * 8;

    if (MODE == 1) {                      // density pre-pass: m-tile = wave
        f32x4 ad = (f32x4){0.f, 0.f, 0.f, 0.f};
        for (int kt = 0; kt < NKT; ++kt) {
            bf16x8 b = *(const bf16x8*)(xb + wave * 16 * XS + kt * 32);
            bf16x8 a = *(const bf16x8*)(Wsw + (size_t)((kt * NT + 16) * 64 + lane) * 8);
            ad = __builtin_amdgcn_mfma_f32_16x16x32_bf16(a, b, ad, 0, 0, 0);
        }
        if (quad == 0)                    // C row 0 = n 256 (density)
            dout[3 * NPTS + p0 + wave * 16 + l15] = fmaxf(ad[0] + bias[256], 0.f);
    }

    f32x4 acc[NS][TM];
#pragma unroll
    for (int s = 0; s < NS; s++)
#pragma unroll
        for (int t = 0; t < TM; t++) acc[s][t] = (f32x4){0.f, 0.f, 0.f, 0.f};

    for (int kt = 0; kt < NKT; ++kt) {
        bf16x8 b[TM];
#pragma unroll
        for (int t = 0; t < TM; t++)
            b[t] = *(const bf16x8*)(xb + (mtB + t) * 16 * XS + kt * 32);
#pragma unroll
        for (int s = 0; s < NS; s++) {
            bf16x8 a = *(const bf16x8*)(Wsw + (size_t)((kt * NT + ntB + s) * 64 + lane) * 8);
#pragma unroll
            for (int t = 0; t < TM; t++)
                acc[s][t] = __builtin_amdgcn_mfma_f32_16x16x32_bf16(a, b[t], acc[s][t], 0, 0, 0);
        }
    }
    __syncthreads();                      // all reads of X done; safe to overwrite
#pragma unroll
    for (int s = 0; s < NS; s++) {
        const int n0 = (ntB + s) * 16 + quad * 4;
        const f32x4 bv = *(const f32x4*)(bias + n0);
#pragma unroll
        for (int t = 0; t < TM; t++) {
            const int m = (mtB + t) * 16 + l15;
            float v0 = acc[s][t][0] + bv[0];
            float v1 = acc[s][t][1] + bv[1];
            float v2 = acc[s][t][2] + bv[2];
            float v3 = acc[s][t][3] + bv[3];
            if (MODE == 0) {
                v0 = fmaxf(v0, 0.f); v1 = fmaxf(v1, 0.f);
                v2 = fmaxf(v2, 0.f); v3 = fmaxf(v3, 0.f);
            }
            u32x2 w; w[0] = pk2(v0, v1); w[1] = pk2(v2, v3);
            *(u32x2*)(X + m * XS + n0) = w;
        }
    }
}

__global__ __launch_bounds__(256, 3) void nerf_fused(Params P) {
    __shared__ __align__(16) short X[MT * XS];
    __shared__ __align__(16) short DE[MT * 32];
    const int tid = threadIdx.x;
    const int wave = tid >> 6, lane = tid & 63;
    const int p0 = blockIdx.x * MT;

    // hidden/out layers: NS=4 n-tiles x TM=4 m-tiles (all 64 points) per wave
    const int ntB_h = wave * 4;
    // r1 (8 n-tiles x 4 m-tiles): NS=2 x TM=4
    const int ntB_r = wave * 2;

    // ---- positional encodings ----
    for (int i = tid; i < MT * 64; i += 256) {
        const int pt = i >> 6, d = i & 63;
        float v = 0.f;
        if (d < 3) v = P.pos[(p0 + pt) * 3 + d];
        else if (d < 63) {
            const int e = d - 3, f = e / 6, r = e % 6;
            const float x = P.pos[(p0 + pt) * 3 + (r % 3)];
            const float xf = x * (float)(1 << f);
            v = (r < 3) ? sinf(xf) : cosf(xf);
        }
        const short bv = f2bf(v);
        X[pt * XS + d] = bv;               // input-layer operand
        X[pt * XS + 256 + d] = bv;         // h4 skip copy
    }
    for (int i = tid; i < MT * 32; i += 256) {
        const int pt = i >> 5, d = i & 31;
        float v = 0.f;
        if (d < 3) v = P.dir[(p0 + pt) * 3 + d];
        else if (d < 27) {
            const int e = d - 3, f = e / 6, r = e % 6;
            const float x = P.dir[(p0 + pt) * 3 + (r % 3)];
            const float xf = x * (float)(1 << f);
            v = (r < 3) ? sinf(xf) : cosf(xf);
        }
        DE[i] = f2bf(v);
    }

    layerT<2, 16, 4, 4, 0>(P.w + OFF_IN, P.b_in, X, P.out, p0, ntB_h, 0, wave, lane);
    layerT<8, 16, 4, 4, 0>(P.w + OFF_H0, P.b_h0, X, P.out, p0, ntB_h, 0, wave, lane);
    layerT<8, 16, 4, 4, 0>(P.w + OFF_H1, P.b_h1, X, P.out, p0, ntB_h, 0, wave, lane);
    layerT<8, 16, 4, 4, 0>(P.w + OFF_H2, P.b_h2, X, P.out, p0, ntB_h, 0, wave, lane);
    layerT<8, 16, 4, 4, 0>(P.w + OFF_H3, P.b_h3, X, P.out, p0, ntB_h, 0, wave, lane);
    layerT<10, 16, 4, 4, 0>(P.w + OFF_H4, P.b_h4, X, P.out, p0, ntB_h, 0, wave, lane); // concat
    layerT<8, 16, 4, 4, 0>(P.w + OFF_H5, P.b_h5, X, P.out, p0, ntB_h, 0, wave, lane);
    layerT<8, 16, 4, 4, 0>(P.w + OFF_H6, P.b_h6, X, P.out, p0, ntB_h, 0, wave, lane);
    layerT<8, 17, 4, 4, 1>(P.w + OFF_OUT, P.b_out, X, P.out, p0, ntB_h, 0, wave, lane);

    // splice de into cols 256..287 (disjoint from feature cols 0..255; ordered
    // before r1's K-loop by r1's entry barrier; cols 283..287 are real zeros)
    for (int i = tid; i < MT * 32; i += 256) {
        const int pt = i >> 5, d = i & 31;
        X[pt * XS + 256 + d] = DE[i];
    }

    layerT<9, 8, 2, 4, 0>(P.w + OFF_R1, P.b_r1, X, P.out, p0, ntB_r, 0, wave, lane);

    // ---- r2 (128 -> 3) + sigmoid; waves 0..3 each take one 16-point tile ----
    __syncthreads();
    {
        const int l15 = lane & 15, quad = lane >> 4;
        f32x4 acc = (f32x4){0.f, 0.f, 0.f, 0.f};
        const short* xb = X + (wave * 16 + l15) * XS + quad * 8;
#pragma unroll
        for (int kt = 0; kt < 4; ++kt) {
            bf16x8 b = *(const bf16x8*)(xb + kt * 32);
            bf16x8 a = *(const bf16x8*)(P.w + OFF_R2 + (size_t)(kt * 64 + lane) * 8);
            acc = __builtin_amdgcn_mfma_f32_16x16x32_bf16(a, b, acc, 0, 0, 0);
        }
        if (quad == 0) {                   // rows r = rgb channel
#pragma unroll
            for (int r = 0; r < 3; r++) {
                const float v = acc[r] + P.b_r2[r];
                P.out[(size_t)(p0 + wave * 16 + l15) * 3 + r] = 1.f / (1.f + expf(-v));
            }
        }
    }
}

extern "C" void kernel_launch(void* const* d_in, const int* in_sizes, int n_in,
                              void* d_out, int out_size, void* d_ws, size_t ws_size,
                              hipStream_t stream) {
    short* ws = (short*)d_ws;

    PrepP pp;
    pp.W[0]  = (const float*)d_in[2];   // W_in
    pp.W[1]  = (const float*)d_in[4];   // W_h0
    pp.W[2]  = (const float*)d_in[6];   // W_h1
    pp.W[3]  = (const float*)d_in[8];   // W_h2
    pp.W[4]  = (const float*)d_in[10];  // W_h3
    pp.W[5]  = (const float*)d_in[12];  // W_h4
    pp.W[6]  = (const float*)d_in[14];  // W_h5
    pp.W[7]  = (const float*)d_in[16];  // W_h6
    pp.W[8]  = (const float*)d_in[18];  // W_out
    pp.W[9]  = (const float*)d_in[20];  // W_r1
    pp.W[10] = (const float*)d_in[22];  // W_r2
    pp.ws = ws;
    hipLaunchKernelGGL(prep_all, dim3((WS_TOTAL + 255) / 256), dim3(256), 0, stream, pp);

    Params P;
    P.pos  = (const float*)d_in[0];
    P.dir  = (const float*)d_in[1];
    P.b_in = (const float*)d_in[3];
    P.b_h0 = (const float*)d_in[5];
    P.b_h1 = (const float*)d_in[7];
    P.b_h2 = (const float*)d_in[9];
    P.b_h3 = (const float*)d_in[11];
    P.b_h4 = (const float*)d_in[13];
    P.b_h5 = (const float*)d_in[15];
    P.b_h6 = (const float*)d_in[17];
    P.b_out = (const float*)d_in[19];
    P.b_r1 = (const float*)d_in[21];
    P.b_r2 = (const float*)d_in[23];
    P.w = ws;
    P.out = (float*)d_out;
    hipLaunchKernelGGL(nerf_fused, dim3(NPTS / MT), dim3(256), 0, stream, P);
}

// Round 7
// 428.529 us; speedup vs baseline: 1.7584x; 1.1630x over previous
//
#include <hip/hip_runtime.h>
#include <math.h>

#define NPTS 262144
#define MT 64          // points per block
#define XS 328         // LDS activation row stride (bf16): 320 + 8 pad (656 B, 16B-aligned)

typedef __attribute__((ext_vector_type(8))) short bf16x8;
typedef __attribute__((ext_vector_type(4))) float f32x4;
typedef __attribute__((ext_vector_type(2))) unsigned int u32x2;

#if defined(__has_builtin)
#if __has_builtin(__builtin_amdgcn_cvt_pk_bf16_f32)
#define HAVE_CVT_PK_BF16 1
#endif
#endif

__device__ __forceinline__ short f2bf(float f) {
    union { float f; unsigned u; } v; v.f = f;
    unsigned r = v.u + 0x7fffu + ((v.u >> 16) & 1u);   // RNE
    return (short)(r >> 16);
}
__device__ __forceinline__ unsigned pk2(float a, float b) {
#ifdef HAVE_CVT_PK_BF16
    auto r = __builtin_amdgcn_cvt_pk_bf16_f32(a, b);   // 1 instr, RNE
    unsigned u; __builtin_memcpy(&u, &r, 4);
    return u;
#else
    return ((unsigned)(unsigned short)f2bf(a)) |
           ((unsigned)(unsigned short)f2bf(b) << 16);
#endif
}

// ---- swizzled-weight workspace layout (offsets in bf16 elements) ----
#define OFF_IN   0
#define SZ_IN    (64*256)
#define OFF_H0   (OFF_IN + SZ_IN)
#define SZ_H     (256*256)
#define OFF_H1   (OFF_H0 + SZ_H)
#define OFF_H2   (OFF_H1 + SZ_H)
#define OFF_H3   (OFF_H2 + SZ_H)
#define OFF_H4   (OFF_H3 + SZ_H)
#define SZ_H4    (320*256)
#define OFF_H5   (OFF_H4 + SZ_H4)
#define OFF_H6   (OFF_H5 + SZ_H)
#define OFF_OUT  (OFF_H6 + SZ_H)
#define SZ_OUT   (256*272)          // N padded to 272 = 17 tiles (density tile = 16)
#define OFF_R1   (OFF_OUT + SZ_OUT)
#define SZ_R1    (288*128)
#define OFF_R2   (OFF_R1 + SZ_R1)
#define SZ_R2    (128*16)
#define WS_TOTAL (OFF_R2 + SZ_R2)

// ---------------- weight prep: f32 -> bf16, 16x16x32 fragment swizzle -------
// frag tile (kt,nt): elem ((kt*nNt + nt)*64 + lane)*8 + j
//   holds W[kt*32 + (lane>>4)*8 + j][nt*16 + (lane&15)]  (0-padded)
// Used as A operand of A=W^T (rows = output feature n): A[m=lane&15][k=quad*8+j].
struct PrepP { const float* W[11]; short* ws; };

__global__ __launch_bounds__(256) void prep_all(PrepP pp) {
    int i = blockIdx.x * 256 + threadIdx.x;
    if (i >= WS_TOTAL) return;
    const int offs[12] = {OFF_IN, OFF_H0, OFF_H1, OFF_H2, OFF_H3, OFF_H4,
                          OFF_H5, OFF_H6, OFF_OUT, OFF_R1, OFF_R2, WS_TOTAL};
    const int Ks[11]  = {63,256,256,256,256,319,256,256,256,283,128};
    const int Ns[11]  = {256,256,256,256,256,256,256,256,257,128,3};
    const int Nps[11] = {256,256,256,256,256,256,256,256,272,128,16};
    int seg = 0;
    while (i >= offs[seg + 1]) seg++;
    int li = i - offs[seg];
    int j = li & 7, L = (li >> 3) & 63, tile = li >> 9;
    int nNt = Nps[seg] >> 4;
    int nt = tile % nNt, kt = tile / nNt;
    int k = kt * 32 + ((L >> 4) << 3) + j;
    int n = nt * 16 + (L & 15);
    float v = (k < Ks[seg] && n < Ns[seg]) ? pp.W[seg][k * Ns[seg] + n] : 0.f;
    pp.ws[i] = f2bf(v);
}

// ---------------- fused MLP ----------------
struct Params {
    const float *pos, *dir;
    const float *b_in, *b_h0, *b_h1, *b_h2, *b_h3, *b_h4, *b_h5, *b_h6;
    const float *b_out, *b_r1, *b_r2;
    const short *w;
    float *out;
};

// Transposed MFMA: A = W^T (rows = feature n), B = X^T (cols = point m).
// C layout: row(quad*4+r) = n-in-tile, col(l15) = m-in-tile -> packed b64 stores.
// 4 waves/block; wave covers NS n-tiles (ntB..) x TM m-tiles (mtB..).
// K-loop is software-pipelined (dist-1 double buffers for a [L2 ~200cyc] and
// b [LDS ~120cyc]); regs: acc 4*NS*TM + 8*(NS+TM) + addr < 170 cap at (256,3).
// MODE 0: relu -> X.  MODE 1: out layer: features (no relu) -> X; density row
// (tile 16, n==256) via a transient 4-wave f32x4 pre-pass straight to gmem.
template<int NKT, int NT, int NS, int TM, int MODE>
__device__ __forceinline__ void layerT(const short* __restrict__ Wsw,
                                       const float* __restrict__ bias,
                                       short* X, float* dout, int p0,
                                       int ntB, int mtB, int wave, int lane) {
    const int l15 = lane & 15, quad = lane >> 4;
    __syncthreads();                      // X (this layer's input) is ready
    const short* xb = X + l15 * XS + quad * 8;

    if (MODE == 1) {                      // density pre-pass: m-tile = wave
        f32x4 ad = (f32x4){0.f, 0.f, 0.f, 0.f};
        for (int kt = 0; kt < NKT; ++kt) {
            bf16x8 b = *(const bf16x8*)(xb + wave * 16 * XS + kt * 32);
            bf16x8 a = *(const bf16x8*)(Wsw + (size_t)((kt * NT + 16) * 64 + lane) * 8);
            ad = __builtin_amdgcn_mfma_f32_16x16x32_bf16(a, b, ad, 0, 0, 0);
        }
        if (quad == 0)                    // C row 0 = n 256 (density)
            dout[3 * NPTS + p0 + wave * 16 + l15] = fmaxf(ad[0] + bias[256], 0.f);
    }

    f32x4 acc[NS][TM];
#pragma unroll
    for (int s = 0; s < NS; s++)
#pragma unroll
        for (int t = 0; t < TM; t++) acc[s][t] = (f32x4){0.f, 0.f, 0.f, 0.f};

    const short* wp = Wsw + (size_t)((ntB)*64 + lane) * 8;   // advances by NT*512/kt

    bf16x8 a_c[NS], b_c[TM];
#pragma unroll
    for (int s = 0; s < NS; s++)
        a_c[s] = *(const bf16x8*)(wp + (size_t)s * 512);
#pragma unroll
    for (int t = 0; t < TM; t++)
        b_c[t] = *(const bf16x8*)(xb + (mtB + t) * 16 * XS);

#pragma unroll
    for (int kt = 0; kt < NKT; ++kt) {
        bf16x8 a_n[NS], b_n[TM];
        if (kt + 1 < NKT) {               // prefetch kt+1 before consuming kt
            const short* wp1 = wp + (size_t)(kt + 1) * NT * 512;
#pragma unroll
            for (int s = 0; s < NS; s++)
                a_n[s] = *(const bf16x8*)(wp1 + (size_t)s * 512);
#pragma unroll
            for (int t = 0; t < TM; t++)
                b_n[t] = *(const bf16x8*)(xb + (mtB + t) * 16 * XS + (kt + 1) * 32);
        }
#pragma unroll
        for (int s = 0; s < NS; s++)
#pragma unroll
            for (int t = 0; t < TM; t++)
                acc[s][t] = __builtin_amdgcn_mfma_f32_16x16x32_bf16(a_c[s], b_c[t], acc[s][t], 0, 0, 0);
        if (kt + 1 < NKT) {
#pragma unroll
            for (int s = 0; s < NS; s++) a_c[s] = a_n[s];
#pragma unroll
            for (int t = 0; t < TM; t++) b_c[t] = b_n[t];
        }
    }
    __syncthreads();                      // all reads of X done; safe to overwrite
#pragma unroll
    for (int s = 0; s < NS; s++) {
        const int n0 = (ntB + s) * 16 + quad * 4;
        const f32x4 bv = *(const f32x4*)(bias + n0);
#pragma unroll
        for (int t = 0; t < TM; t++) {
            const int m = (mtB + t) * 16 + l15;
            float v0 = acc[s][t][0] + bv[0];
            float v1 = acc[s][t][1] + bv[1];
            float v2 = acc[s][t][2] + bv[2];
            float v3 = acc[s][t][3] + bv[3];
            if (MODE == 0) {
                v0 = fmaxf(v0, 0.f); v1 = fmaxf(v1, 0.f);
                v2 = fmaxf(v2, 0.f); v3 = fmaxf(v3, 0.f);
            }
            u32x2 w; w[0] = pk2(v0, v1); w[1] = pk2(v2, v3);
            *(u32x2*)(X + m * XS + n0) = w;
        }
    }
}

__global__ __launch_bounds__(256, 3) void nerf_fused(Params P) {
    __shared__ __align__(16) short X[MT * XS];
    __shared__ __align__(16) short DE[MT * 32];
    const int tid = threadIdx.x;
    const int wave = tid >> 6, lane = tid & 63;
    const int p0 = blockIdx.x * MT;

    // hidden/out layers: NS=4 n-tiles x TM=4 m-tiles (all 64 points) per wave
    const int ntB_h = wave * 4;
    // r1 (8 n-tiles x 4 m-tiles): NS=2 x TM=4
    const int ntB_r = wave * 2;

    // ---- positional encodings ----
    for (int i = tid; i < MT * 64; i += 256) {
        const int pt = i >> 6, d = i & 63;
        float v = 0.f;
        if (d < 3) v = P.pos[(p0 + pt) * 3 + d];
        else if (d < 63) {
            const int e = d - 3, f = e / 6, r = e % 6;
            const float x = P.pos[(p0 + pt) * 3 + (r % 3)];
            const float xf = x * (float)(1 << f);
            v = (r < 3) ? sinf(xf) : cosf(xf);
        }
        const short bv = f2bf(v);
        X[pt * XS + d] = bv;               // input-layer operand
        X[pt * XS + 256 + d] = bv;         // h4 skip copy
    }
    for (int i = tid; i < MT * 32; i += 256) {
        const int pt = i >> 5, d = i & 31;
        float v = 0.f;
        if (d < 3) v = P.dir[(p0 + pt) * 3 + d];
        else if (d < 27) {
            const int e = d - 3, f = e / 6, r = e % 6;
            const float x = P.dir[(p0 + pt) * 3 + (r % 3)];
            const float xf = x * (float)(1 << f);
            v = (r < 3) ? sinf(xf) : cosf(xf);
        }
        DE[i] = f2bf(v);
    }

    layerT<2, 16, 4, 4, 0>(P.w + OFF_IN, P.b_in, X, P.out, p0, ntB_h, 0, wave, lane);
    layerT<8, 16, 4, 4, 0>(P.w + OFF_H0, P.b_h0, X, P.out, p0, ntB_h, 0, wave, lane);
    layerT<8, 16, 4, 4, 0>(P.w + OFF_H1, P.b_h1, X, P.out, p0, ntB_h, 0, wave, lane);
    layerT<8, 16, 4, 4, 0>(P.w + OFF_H2, P.b_h2, X, P.out, p0, ntB_h, 0, wave, lane);
    layerT<8, 16, 4, 4, 0>(P.w + OFF_H3, P.b_h3, X, P.out, p0, ntB_h, 0, wave, lane);
    layerT<10, 16, 4, 4, 0>(P.w + OFF_H4, P.b_h4, X, P.out, p0, ntB_h, 0, wave, lane); // concat
    layerT<8, 16, 4, 4, 0>(P.w + OFF_H5, P.b_h5, X, P.out, p0, ntB_h, 0, wave, lane);
    layerT<8, 16, 4, 4, 0>(P.w + OFF_H6, P.b_h6, X, P.out, p0, ntB_h, 0, wave, lane);
    layerT<8, 17, 4, 4, 1>(P.w + OFF_OUT, P.b_out, X, P.out, p0, ntB_h, 0, wave, lane);

    // splice de into cols 256..287 (disjoint from feature cols 0..255; ordered
    // before r1's K-loop by r1's entry barrier; cols 283..287 are real zeros)
    for (int i = tid; i < MT * 32; i += 256) {
        const int pt = i >> 5, d = i & 31;
        X[pt * XS + 256 + d] = DE[i];
    }

    layerT<9, 8, 2, 4, 0>(P.w + OFF_R1, P.b_r1, X, P.out, p0, ntB_r, 0, wave, lane);

    // ---- r2 (128 -> 3) + sigmoid; waves 0..3 each take one 16-point tile ----
    __syncthreads();
    {
        const int l15 = lane & 15, quad = lane >> 4;
        f32x4 acc = (f32x4){0.f, 0.f, 0.f, 0.f};
        const short* xb = X + (wave * 16 + l15) * XS + quad * 8;
#pragma unroll
        for (int kt = 0; kt < 4; ++kt) {
            bf16x8 b = *(const bf16x8*)(xb + kt * 32);
            bf16x8 a = *(const bf16x8*)(P.w + OFF_R2 + (size_t)(kt * 64 + lane) * 8);
            acc = __builtin_amdgcn_mfma_f32_16x16x32_bf16(a, b, acc, 0, 0, 0);
        }
        if (quad == 0) {                   // rows r = rgb channel
#pragma unroll
            for (int r = 0; r < 3; r++) {
                const float v = acc[r] + P.b_r2[r];
                P.out[(size_t)(p0 + wave * 16 + l15) * 3 + r] = 1.f / (1.f + expf(-v));
            }
        }
    }
}

extern "C" void kernel_launch(void* const* d_in, const int* in_sizes, int n_in,
                              void* d_out, int out_size, void* d_ws, size_t ws_size,
                              hipStream_t stream) {
    short* ws = (short*)d_ws;

    PrepP pp;
    pp.W[0]  = (const float*)d_in[2];   // W_in
    pp.W[1]  = (const float*)d_in[4];   // W_h0
    pp.W[2]  = (const float*)d_in[6];   // W_h1
    pp.W[3]  = (const float*)d_in[8];   // W_h2
    pp.W[4]  = (const float*)d_in[10];  // W_h3
    pp.W[5]  = (const float*)d_in[12];  // W_h4
    pp.W[6]  = (const float*)d_in[14];  // W_h5
    pp.W[7]  = (const float*)d_in[16];  // W_h6
    pp.W[8]  = (const float*)d_in[18];  // W_out
    pp.W[9]  = (const float*)d_in[20];  // W_r1
    pp.W[10] = (const float*)d_in[22];  // W_r2
    pp.ws = ws;
    hipLaunchKernelGGL(prep_all, dim3((WS_TOTAL + 255) / 256), dim3(256), 0, stream, pp);

    Params P;
    P.pos  = (const float*)d_in[0];
    P.dir  = (const float*)d_in[1];
    P.b_in = (const float*)d_in[3];
    P.b_h0 = (const float*)d_in[5];
    P.b_h1 = (const float*)d_in[7];
    P.b_h2 = (const float*)d_in[9];
    P.b_h3 = (const float*)d_in[11];
    P.b_h4 = (const float*)d_in[13];
    P.b_h5 = (const float*)d_in[15];
    P.b_h6 = (const float*)d_in[17];
    P.b_out = (const float*)d_in[19];
    P.b_r1 = (const float*)d_in[21];
    P.b_r2 = (const float*)d_in[23];
    P.w = ws;
    P.out = (float*)d_out;
    hipLaunchKernelGGL(nerf_fused, dim3(NPTS / MT), dim3(256), 0, stream, P);
}